// Round 11
// baseline (254.810 us; speedup 1.0000x reference)
//
#include <hip/hip_runtime.h>
#include <hip/hip_bf16.h>

#define HW1K  1048576    // 1024*1024

typedef float f4 __attribute__((ext_vector_type(4)));

__device__ __forceinline__ f4 relu4(f4 v) {
    v.x = fmaxf(v.x, 0.0f); v.y = fmaxf(v.y, 0.0f);
    v.z = fmaxf(v.z, 0.0f); v.w = fmaxf(v.w, 0.0f);
    return v;
}

// Weight-prep: OIHW -> wp[layer_base + (ci*9+ky*3+kx)*COUT + co] (co fastest).
// Bases: L1@0(432) L2@432(4608) L3@5040(9216) L4@14256(18432) L5@32688(36864)
// L6@69552(55296), total 124848.
__global__ void prep_w(const float* __restrict__ w1, const float* __restrict__ w2,
                       const float* __restrict__ w3, const float* __restrict__ w4,
                       const float* __restrict__ w5, const float* __restrict__ w6,
                       float* __restrict__ wp) {
    int i = blockIdx.x * 256 + threadIdx.x;
    if (i >= 124848) return;
    const float* src; int base, cin, cout;
    if      (i < 432)   { src = w1; base = 0;     cin = 3;  cout = 16; }
    else if (i < 5040)  { src = w2; base = 432;   cin = 16; cout = 32; }
    else if (i < 14256) { src = w3; base = 5040;  cin = 32; cout = 32; }
    else if (i < 32688) { src = w4; base = 14256; cin = 32; cout = 64; }
    else if (i < 69552) { src = w5; base = 32688; cin = 64; cout = 64; }
    else                { src = w6; base = 69552; cin = 64; cout = 96; }
    int r  = i - base;
    int kk = r / cout;
    int co = r % cout;
    int ci = kk / 9;
    int t9 = kk % 9;
    wp[i] = src[(co * cin + ci) * 9 + t9];
}

// ---------------------------------------------------------------------------
// xin: per-cell 14x14x(3+pad) cone of the 4x-downsampled input -> A0[cell][196][4].
// xlow[y][x] = avg of x rows 4y+1..4y+2, cols 4x+1..4x+2 (exact bilinear).
// cell = b*256 + gy*16 + gx; cone coords in [1,254]: padding never triggers.
__global__ __launch_bounds__(256)
void xinK(const float* __restrict__ x, float* __restrict__ A0) {
    int idx = blockIdx.x * 256 + threadIdx.x;
    if (idx >= 512 * 196) return;
    int cell = idx / 196, t = idx % 196;
    int xi = t % 14, yi = t / 14;
    int b = cell >> 8, gy = (cell >> 4) & 15, gx = cell & 15;
    int ya = 16 * gy + 1 + yi, xa = 16 * gx + 1 + xi;
    f4 o;
    #pragma unroll
    for (int c = 0; c < 3; ++c) {
        const float* p = x + ((size_t)(b * 3 + c)) * HW1K + (4 * ya + 1) * 1024 + (4 * xa + 1);
        o[c] = 0.25f * (p[0] + p[1] + p[1024] + p[1025]);
    }
    o[3] = 0.0f;
    *(f4*)(A0 + (size_t)cell * 784 + t * 4) = o;
}

// ---------------------------------------------------------------------------
// conv1: CIN=3 special (scalar act reads). Block=cell. out A1[cell][144][16].
__global__ __launch_bounds__(256)
void conv1K(const float* __restrict__ A0, float* __restrict__ A1,
            const float* __restrict__ wp, const float* __restrict__ bias) {
    __shared__ float s[784];
    const int cell = blockIdx.x;
    for (int i = threadIdx.x; i < 196; i += 256)
        *(f4*)(s + i * 4) = *(const f4*)(A0 + (size_t)cell * 784 + i * 4);
    __syncthreads();

    const int cog = threadIdx.x % 4, co0 = cog * 4, ps = threadIdx.x / 4;
    const f4 bs = *(const f4*)(bias + co0);
    #pragma unroll 1
    for (int s3 = 0; s3 < 3; ++s3) {
        int px = ps + s3 * 64; if (px > 143) px = 143;
        const int base = ((px / 12) * 14 + (px % 12)) * 4;
        f4 acc = bs;
        for (int ci = 0; ci < 3; ++ci) {
            #pragma unroll
            for (int k = 0; k < 9; ++k) {
                f4 w = *(const f4*)(wp + (ci * 9 + k) * 16 + co0);
                acc += w * s[base + ((k / 3) * 14 + (k % 3)) * 4 + ci];
            }
        }
        *(f4*)(A1 + (size_t)cell * 2304 + px * 16 + co0) = relu4(acc);
    }
}

// ---------------------------------------------------------------------------
// Universal conv layer: block = (cell, cout-tile of COT). Stage input tile
// [WIN^2][CIN] -> LDS (SI=CIN+4 pad), then R6-proven inner loop.
// STRIP=1: thread = (cog -> 4 co, 1x2 px strip). STRIP=0: 1 px per thread.
// Clamped duplicate slots redo last unit (same value, benign).
template <int WIN, int CIN, int COUT, int COT, int STRIP, int RELU>
__global__ __launch_bounds__(256)
void convL(const float* __restrict__ Ain, float* __restrict__ Aout,
           const float* __restrict__ wp, const float* __restrict__ bias) {
    constexpr int WOUT = WIN - 2;
    constexpr int NPX  = WOUT * WOUT;
    constexpr int NPIN = WIN * WIN;
    constexpr int SI   = CIN + 4;
    constexpr int COG  = COT / 4;

    __shared__ float sIn[NPIN * SI];
    const int cell = blockIdx.x;
    const int co0g = blockIdx.y * COT;

    for (int i = threadIdx.x; i < NPIN * CIN / 4; i += 256) {
        int px = i / (CIN / 4), c4 = i % (CIN / 4);
        *(f4*)(sIn + px * SI + c4 * 4) =
            *(const f4*)(Ain + (size_t)cell * NPIN * CIN + px * CIN + c4 * 4);
    }
    __syncthreads();

    const int cog = threadIdx.x % COG;
    const int co0 = co0g + cog * 4;
    const int ps  = threadIdx.x / COG;
    const f4 bs   = *(const f4*)(bias + co0);
    const float* wb = wp + co0;

    if (STRIP) {
        constexpr int HSTR = WOUT / 2;
        constexpr int NSTR = WOUT * HSTR;
        int ss = ps < NSTR ? ps : NSTR - 1;
        const int row  = ss / HSTR;
        const int col2 = (ss % HSTR) * 2;
        const int base = (row * WIN + col2) * SI;

        f4 acc0 = bs, acc1 = bs;
        for (int ci4 = 0; ci4 < CIN / 4; ++ci4) {
            f4 a[3][4];
            #pragma unroll
            for (int r = 0; r < 3; ++r)
                #pragma unroll
                for (int c = 0; c < 4; ++c)
                    a[r][c] = *(const f4*)(sIn + base + (r * WIN + c) * SI + ci4 * 4);
            #pragma unroll
            for (int cc = 0; cc < 4; ++cc)
                #pragma unroll
                for (int ky = 0; ky < 3; ++ky)
                    #pragma unroll
                    for (int kx = 0; kx < 3; ++kx) {
                        f4 w = *(const f4*)(wb + ((ci4 * 4 + cc) * 9 + ky * 3 + kx) * COUT);
                        acc0 += w * a[ky][kx][cc];
                        acc1 += w * a[ky][kx + 1][cc];
                    }
        }
        const int opx = row * WOUT + col2;
        float* o = Aout + (size_t)cell * NPX * COUT + opx * COUT + co0;
        *(f4*)o          = RELU ? relu4(acc0) : acc0;
        *(f4*)(o + COUT) = RELU ? relu4(acc1) : acc1;
    } else {
        int px = ps < NPX ? ps : NPX - 1;
        const int row = px / WOUT, col = px % WOUT;
        const int base = (row * WIN + col) * SI;

        f4 acc = bs;
        for (int ci4 = 0; ci4 < CIN / 4; ++ci4) {
            f4 a[3][3];
            #pragma unroll
            for (int r = 0; r < 3; ++r)
                #pragma unroll
                for (int c = 0; c < 3; ++c)
                    a[r][c] = *(const f4*)(sIn + base + (r * WIN + c) * SI + ci4 * 4);
            #pragma unroll
            for (int cc = 0; cc < 4; ++cc)
                #pragma unroll
                for (int k = 0; k < 9; ++k) {
                    f4 w = *(const f4*)(wb + ((ci4 * 4 + cc) * 9 + k) * COUT);
                    acc += w * a[k / 3][k % 3][cc];
                }
        }
        *(f4*)(Aout + (size_t)cell * NPX * COUT + px * COUT + co0) =
            RELU ? relu4(acc) : acc;
    }
}

// ---------------------------------------------------------------------------
// conv6 + 2x2 pool: block = (cell, co-half of 48). ci-split x4 quarters
// (192 active threads), partials via LDS, pool+bias in combine, write c16.
__global__ __launch_bounds__(256)
void conv6K(const float* __restrict__ A5, float* __restrict__ c16,
            const float* __restrict__ wp, const float* __restrict__ bias) {
    __shared__ float sIn[16 * 68];
    __shared__ float sP[4 * 4 * 48];   // [quarter][px][48ch]

    const int cell = blockIdx.x;
    const int co0g = blockIdx.y * 48;

    {
        int i = threadIdx.x;           // 256 = 16px * 16 c4 exactly
        int px = i / 16, c4 = i % 16;
        *(f4*)(sIn + px * 68 + c4 * 4) =
            *(const f4*)(A5 + (size_t)cell * 1024 + px * 64 + c4 * 4);
    }
    __syncthreads();

    const int q = threadIdx.x >> 6;
    const int r = threadIdx.x & 63;
    if (r < 48) {
        const int px = r / 12, cog = r % 12, co0 = co0g + cog * 4;
        const int base = ((px >> 1) * 4 + (px & 1)) * 68;
        f4 acc = {0.f, 0.f, 0.f, 0.f};
        for (int ci4 = q * 4; ci4 < q * 4 + 4; ++ci4) {
            f4 a[3][3];
            #pragma unroll
            for (int rr = 0; rr < 3; ++rr)
                #pragma unroll
                for (int c = 0; c < 3; ++c)
                    a[rr][c] = *(const f4*)(sIn + base + (rr * 4 + c) * 68 + ci4 * 4);
            #pragma unroll
            for (int cc = 0; cc < 4; ++cc)
                #pragma unroll
                for (int k = 0; k < 9; ++k) {
                    f4 w = *(const f4*)(wp + ((ci4 * 4 + cc) * 9 + k) * 96 + co0);
                    acc += w * a[k / 3][k % 3][cc];
                }
        }
        *(f4*)(sP + q * 192 + px * 48 + cog * 4) = acc;
    }
    __syncthreads();

    if (threadIdx.x < 48) {
        const int ch = threadIdx.x;
        const int co = co0g + ch;
        float v = 0.0f;
        #pragma unroll
        for (int qq = 0; qq < 4; ++qq)
            #pragma unroll
            for (int px = 0; px < 4; ++px)
                v += sP[qq * 192 + px * 48 + ch];
        v = 0.25f * v + bias[co];
        const int b = cell >> 8, gy = (cell >> 4) & 15, gx = cell & 15;
        const int p = co >> 3, d = co & 7;
        c16[(size_t)b * 24576 + ((gy * 16 + gx) * 8 + d) * 12 + p] = v;
    }
}

// ---------------------------------------------------------------------------
// Fused guide + trilinear slice + affine + clip; 4 px per thread (float4).
// c16 layout: [b][gy*16+gx][d][p=12].
__global__ __launch_bounds__(256)
void slice_apply4(const float* __restrict__ x, const float* __restrict__ c16,
                  float* __restrict__ out) {
    int t = blockIdx.x * 256 + threadIdx.x;      // 0 .. 2*HW1K/4 - 1
    int po4 = t * 4;
    int b   = po4 >> 20;
    int po  = po4 & (HW1K - 1);
    int py  = po >> 10;
    int px0 = po & 1023;

    const float* xb = x + (size_t)b * 3 * HW1K;
    f4 rv  = *(const f4*)(xb + po);
    f4 gv  = *(const f4*)(xb + HW1K + po);
    f4 bv  = *(const f4*)(xb + 2 * HW1K + po);

    float ysf = (float)py * (15.0f / 1023.0f);
    int y0 = (int)floorf(ysf); int y1 = min(y0 + 1, 15);
    float wy = ysf - (float)y0;

    const float* gb = c16 + (size_t)b * 24576;
    f4 outv[3];

    #pragma unroll
    for (int s = 0; s < 4; ++s) {
        float r  = rv[s], g = gv[s], bl = bv[s];
        int   px = px0 + s;

        float gd = fminf(fmaxf(0.299f * r + 0.587f * g + 0.114f * bl, 0.0f), 1.0f);

        float xsf = (float)px * (15.0f / 1023.0f);
        int x0 = (int)floorf(xsf); int x1 = min(x0 + 1, 15);
        float wx = xsf - (float)x0;

        float d  = gd * 7.0f;
        int d0 = (int)floorf(d); d0 = max(0, min(d0, 7));
        int d1 = min(d0 + 1, 7);
        float wd = fminf(fmaxf(d - (float)d0, 0.0f), 1.0f);

        float co[12];
        #pragma unroll
        for (int p = 0; p < 12; ++p) co[p] = 0.0f;

        #pragma unroll
        for (int cy = 0; cy < 2; ++cy) {
            int   yy  = cy ? y1 : y0;
            float wyf = cy ? wy : 1.0f - wy;
            #pragma unroll
            for (int cx = 0; cx < 2; ++cx) {
                int   xx  = cx ? x1 : x0;
                float wyx = wyf * (cx ? wx : 1.0f - wx);
                const float* g0 = gb + ((yy * 16 + xx) * 8 + d0) * 12;
                const float* g1 = gb + ((yy * 16 + xx) * 8 + d1) * 12;
                float wA = wyx * (1.0f - wd), wB = wyx * wd;
                #pragma unroll
                for (int p = 0; p < 12; ++p) co[p] += wA * g0[p] + wB * g1[p];
            }
        }

        #pragma unroll
        for (int i = 0; i < 3; ++i) {
            float v = co[i * 4 + 0] * r + co[i * 4 + 1] * g + co[i * 4 + 2] * bl + co[i * 4 + 3];
            outv[i][s] = fminf(fmaxf(v, 0.0f), 1.0f);
        }
    }

    float* ob = out + (size_t)b * 3 * HW1K;
    #pragma unroll
    for (int i = 0; i < 3; ++i)
        *(f4*)(ob + i * HW1K + po) = outv[i];
}

// ---------------------------------------------------------------------------
extern "C" void kernel_launch(void* const* d_in, const int* in_sizes, int n_in,
                              void* d_out, int out_size, void* d_ws, size_t ws_size,
                              hipStream_t stream) {
    const float* x  = (const float*)d_in[0];
    const float* w1 = (const float*)d_in[1];  const float* b1 = (const float*)d_in[2];
    const float* w2 = (const float*)d_in[3];  const float* b2 = (const float*)d_in[4];
    const float* w3 = (const float*)d_in[5];  const float* b3 = (const float*)d_in[6];
    const float* w4 = (const float*)d_in[7];  const float* b4 = (const float*)d_in[8];
    const float* w5 = (const float*)d_in[9];  const float* b5 = (const float*)d_in[10];
    const float* w6 = (const float*)d_in[11]; const float* b6 = (const float*)d_in[12];
    float* out = (float*)d_out;

    // Workspace (floats):
    float* wp  = (float*)d_ws;        // 124848 (+pad)
    float* A0  = wp  + 126000;        // 512*196*4   = 401408
    float* A1  = A0  + 401408;        // 512*144*16  = 1179648
    float* A2  = A1  + 1179648;       // 512*100*32  = 1638400
    float* A3  = A2  + 1638400;       // 512*64*32   = 1048576
    float* A4  = A3  + 1048576;       // 512*36*64   = 1179648
    float* A5  = A4  + 1179648;       // 512*16*64   = 524288
    float* c16 = A5  + 524288;        // 2*24576     = 49152

    prep_w<<<dim3(488), dim3(256), 0, stream>>>(w1, w2, w3, w4, w5, w6, wp);
    xinK  <<<dim3(392), dim3(256), 0, stream>>>(x, A0);
    conv1K<<<dim3(512), dim3(256), 0, stream>>>(A0, A1, wp, b1);
    convL<12, 16, 32, 16, 1, 1><<<dim3(512, 2), dim3(256), 0, stream>>>(A1, A2, wp + 432,   b2);
    convL<10, 32, 32, 32, 1, 1><<<dim3(512, 1), dim3(256), 0, stream>>>(A2, A3, wp + 5040,  b3);
    convL< 8, 32, 64, 32, 1, 1><<<dim3(512, 2), dim3(256), 0, stream>>>(A3, A4, wp + 14256, b4);
    convL< 6, 64, 64, 32, 0, 1><<<dim3(512, 2), dim3(256), 0, stream>>>(A4, A5, wp + 32688, b5);
    conv6K<<<dim3(512, 2), dim3(256), 0, stream>>>(A5, c16, wp + 69552, b6);
    slice_apply4<<<dim3(2 * HW1K / 4 / 256), dim3(256), 0, stream>>>(x, c16, out);

    (void)in_sizes; (void)n_in; (void)out_size; (void)ws_size;
}

// Round 12
// 189.995 us; speedup vs baseline: 1.3411x; 1.3411x over previous
//
#include <hip/hip_runtime.h>
#include <hip/hip_bf16.h>

#define HW1K  1048576    // 1024*1024

typedef float f4 __attribute__((ext_vector_type(4)));

// Weight-prep: OIHW -> wp[layer_base + (ci*9+k)*COUT + co].
// Bases: L1@0(432) L2@432(4608) L3@5040(9216) L4@14256(18432) L5@32688(36864)
// L6@69552(55296), total 124848.
__global__ void prep_w(const float* __restrict__ w1, const float* __restrict__ w2,
                       const float* __restrict__ w3, const float* __restrict__ w4,
                       const float* __restrict__ w5, const float* __restrict__ w6,
                       float* __restrict__ wp) {
    int i = blockIdx.x * 256 + threadIdx.x;
    if (i >= 124848) return;
    const float* src; int base, cin, cout;
    if      (i < 432)   { src = w1; base = 0;     cin = 3;  cout = 16; }
    else if (i < 5040)  { src = w2; base = 432;   cin = 16; cout = 32; }
    else if (i < 14256) { src = w3; base = 5040;  cin = 32; cout = 32; }
    else if (i < 32688) { src = w4; base = 14256; cin = 32; cout = 64; }
    else if (i < 69552) { src = w5; base = 32688; cin = 64; cout = 64; }
    else                { src = w6; base = 69552; cin = 64; cout = 96; }
    int r  = i - base;
    int kk = r / cout;
    int co = r % cout;
    int ci = kk / 9;
    int t9 = kk % 9;
    wp[i] = src[(co * cin + ci) * 9 + t9];
}

// ---------------------------------------------------------------------------
// xin: A0[cell][c][196] = 14x14 cone of the 4x-downsampled input.
// xlow[y][x] = avg of x rows 4y+1..4y+2, cols 4x+1..4x+2 (exact bilinear).
// cell = b*256+gy*16+gx; cone coords in [1,254]: padding never triggers.
__global__ __launch_bounds__(256)
void xinK(const float* __restrict__ x, float* __restrict__ A0) {
    int idx = blockIdx.x * 256 + threadIdx.x;
    if (idx >= 512 * 588) return;
    int cell = idx / 588, r = idx % 588;
    int c = r / 196, t = r % 196;
    int xi = t % 14, yi = t / 14;
    int b = cell >> 8, gy = (cell >> 4) & 15, gx = cell & 15;
    int ya = 16 * gy + 1 + yi, xa = 16 * gx + 1 + xi;
    const float* p = x + ((size_t)(b * 3 + c)) * HW1K + (4 * ya + 1) * 1024 + (4 * xa + 1);
    A0[idx] = 0.25f * (p[0] + p[1] + p[1024] + p[1025]);
}

// ---------------------------------------------------------------------------
// Universal wave-uniform-co conv layer, 256 threads = 4 waves.
// Grid = (cells/CPB, coTiles). Wave wid -> co0 = (blockIdx.y*4+wid)*NCO
// (wave-uniform via readfirstlane => weight/bias reads become s_load through
// the constant cache: NO vector-memory weight traffic). Lanes = pixels
// (CPB cells x LPC=64/CPB lane-slots, PPL px per lane, clamp-dup benign).
// Acts staged [cell][ci][NPIN] in LDS, cell stride +4 pad (bank spread);
// per (ci,k): NCO s_loads + PPL ds_read_b32 + NCO*PPL v_fma(v,s,v,v).
// POOL=1 (L6): 2x2 avg via shfl_xor over the 4 px-lanes + write c16 layout
// [b][gy*16+gx][d][p]; bias folded (init bias, sum 4 lanes, *0.25).
template <int WIN, int CIN, int COUT, int NCO, int CPB, int PPL, int POOL>
__global__ __launch_bounds__(256)
void convU(const float* __restrict__ Ain, float* __restrict__ Aout,
           const float* __restrict__ wp, const float* __restrict__ bias) {
    constexpr int WOUT = WIN - 2;
    constexpr int NPX  = WOUT * WOUT;
    constexpr int NPIN = WIN * WIN;
    constexpr int LPC  = 64 / CPB;
    constexpr int CSTR = CIN * NPIN + 4;       // LDS cell stride (+4 bank pad)
    constexpr int PC4  = CIN * NPIN / 4;       // f4 copies per cell

    __shared__ float s[CPB * CSTR];

    const int cell0 = blockIdx.x * CPB;

    for (int i = threadIdx.x; i < CPB * PC4; i += 256) {
        int c = i / PC4, r = i % PC4;
        *(f4*)(s + c * CSTR + r * 4) =
            *(const f4*)(Ain + ((size_t)(cell0 + c) * CIN * NPIN) + r * 4);
    }
    __syncthreads();

    const int wid  = __builtin_amdgcn_readfirstlane(threadIdx.x >> 6);
    const int lane = threadIdx.x & 63;
    const int co0  = (blockIdx.y * 4 + wid) * NCO;     // wave-uniform
    const int cl   = lane / LPC;
    const int pxl  = lane % LPC;

    int pxs[PPL], base[PPL];
    #pragma unroll
    for (int t = 0; t < PPL; ++t) {
        int p = pxl + t * LPC; if (p > NPX - 1) p = NPX - 1;
        pxs[t]  = p;
        base[t] = cl * CSTR + (p / WOUT) * WIN + (p % WOUT);
    }

    float acc[PPL][NCO];
    #pragma unroll
    for (int t = 0; t < PPL; ++t)
        #pragma unroll
        for (int j = 0; j < NCO; ++j)
            acc[t][j] = bias[co0 + j];                  // uniform s_load

    const float* wb = wp + co0;
    for (int ci = 0; ci < CIN; ++ci) {
        #pragma unroll
        for (int k = 0; k < 9; ++k) {
            const int koff = (k / 3) * WIN + (k % 3) + ci * NPIN;
            float w[NCO];
            #pragma unroll
            for (int j = 0; j < NCO; ++j)
                w[j] = wb[(ci * 9 + k) * COUT + j];     // uniform -> s_load
            #pragma unroll
            for (int t = 0; t < PPL; ++t) {
                float a = s[base[t] + koff];            // lane-varying ds_read
                #pragma unroll
                for (int j = 0; j < NCO; ++j)
                    acc[t][j] = fmaf(w[j], a, acc[t][j]);
            }
        }
    }

    if (!POOL) {
        const size_t ob = (size_t)(cell0 + cl) * COUT * NPX;
        #pragma unroll
        for (int t = 0; t < PPL; ++t)
            #pragma unroll
            for (int j = 0; j < NCO; ++j)
                Aout[ob + (co0 + j) * NPX + pxs[t]] = fmaxf(acc[0 + t][j], 0.0f);
    } else {
        // NPX==4, LPC==4, PPL==1: avg over the 4 px-lanes of this cell.
        float v[NCO];
        #pragma unroll
        for (int j = 0; j < NCO; ++j) {
            float t = acc[0][j];
            t += __shfl_xor(t, 1, 64);
            t += __shfl_xor(t, 2, 64);
            v[j] = 0.25f * t;                           // bias: 4*b*0.25 = b
        }
        if (pxl == 0) {
            const int cell = cell0 + cl;
            const int b = cell >> 8, gyx = cell & 255;
            #pragma unroll
            for (int j = 0; j < NCO; ++j) {
                const int co = co0 + j;
                Aout[(size_t)b * 24576 + (gyx * 8 + (co & 7)) * 12 + (co >> 3)] = v[j];
            }
        }
    }
}

// ---------------------------------------------------------------------------
// Fused guide + trilinear slice + affine + clip; 4 px per thread (float4).
// c16 layout: [b][gy*16+gx][d][p=12].
__global__ __launch_bounds__(256)
void slice_apply4(const float* __restrict__ x, const float* __restrict__ c16,
                  float* __restrict__ out) {
    int t = blockIdx.x * 256 + threadIdx.x;      // 0 .. 2*HW1K/4 - 1
    int po4 = t * 4;
    int b   = po4 >> 20;
    int po  = po4 & (HW1K - 1);
    int py  = po >> 10;
    int px0 = po & 1023;

    const float* xb = x + (size_t)b * 3 * HW1K;
    f4 rv  = *(const f4*)(xb + po);
    f4 gv  = *(const f4*)(xb + HW1K + po);
    f4 bv  = *(const f4*)(xb + 2 * HW1K + po);

    float ysf = (float)py * (15.0f / 1023.0f);
    int y0 = (int)floorf(ysf); int y1 = min(y0 + 1, 15);
    float wy = ysf - (float)y0;

    const float* gb = c16 + (size_t)b * 24576;
    f4 outv[3];

    #pragma unroll
    for (int s = 0; s < 4; ++s) {
        float r  = rv[s], g = gv[s], bl = bv[s];
        int   px = px0 + s;

        float gd = fminf(fmaxf(0.299f * r + 0.587f * g + 0.114f * bl, 0.0f), 1.0f);

        float xsf = (float)px * (15.0f / 1023.0f);
        int x0 = (int)floorf(xsf); int x1 = min(x0 + 1, 15);
        float wx = xsf - (float)x0;

        float d  = gd * 7.0f;
        int d0 = (int)floorf(d); d0 = max(0, min(d0, 7));
        int d1 = min(d0 + 1, 7);
        float wd = fminf(fmaxf(d - (float)d0, 0.0f), 1.0f);

        float co[12];
        #pragma unroll
        for (int p = 0; p < 12; ++p) co[p] = 0.0f;

        #pragma unroll
        for (int cy = 0; cy < 2; ++cy) {
            int   yy  = cy ? y1 : y0;
            float wyf = cy ? wy : 1.0f - wy;
            #pragma unroll
            for (int cx = 0; cx < 2; ++cx) {
                int   xx  = cx ? x1 : x0;
                float wyx = wyf * (cx ? wx : 1.0f - wx);
                const float* g0 = gb + ((yy * 16 + xx) * 8 + d0) * 12;
                const float* g1 = gb + ((yy * 16 + xx) * 8 + d1) * 12;
                float wA = wyx * (1.0f - wd), wB = wyx * wd;
                #pragma unroll
                for (int p = 0; p < 12; ++p) co[p] += wA * g0[p] + wB * g1[p];
            }
        }

        #pragma unroll
        for (int i = 0; i < 3; ++i) {
            float v = co[i * 4 + 0] * r + co[i * 4 + 1] * g + co[i * 4 + 2] * bl + co[i * 4 + 3];
            outv[i][s] = fminf(fmaxf(v, 0.0f), 1.0f);
        }
    }

    float* ob = out + (size_t)b * 3 * HW1K;
    #pragma unroll
    for (int i = 0; i < 3; ++i)
        *(f4*)(ob + i * HW1K + po) = outv[i];
}

// ---------------------------------------------------------------------------
extern "C" void kernel_launch(void* const* d_in, const int* in_sizes, int n_in,
                              void* d_out, int out_size, void* d_ws, size_t ws_size,
                              hipStream_t stream) {
    const float* x  = (const float*)d_in[0];
    const float* w1 = (const float*)d_in[1];  const float* b1 = (const float*)d_in[2];
    const float* w2 = (const float*)d_in[3];  const float* b2 = (const float*)d_in[4];
    const float* w3 = (const float*)d_in[5];  const float* b3 = (const float*)d_in[6];
    const float* w4 = (const float*)d_in[7];  const float* b4 = (const float*)d_in[8];
    const float* w5 = (const float*)d_in[9];  const float* b5 = (const float*)d_in[10];
    const float* w6 = (const float*)d_in[11]; const float* b6 = (const float*)d_in[12];
    float* out = (float*)d_out;

    // Workspace (floats):
    float* wp  = (float*)d_ws;        // 124848 (+pad)
    float* A0  = wp  + 126000;        // 512*3*196  = 301056
    float* A1  = A0  + 301056;        // 512*16*144 = 1179648
    float* A2  = A1  + 1179648;       // 512*32*100 = 1638400
    float* A3  = A2  + 1638400;       // 512*32*64  = 1048576
    float* A4  = A3  + 1048576;       // 512*64*36  = 1179648
    float* A5  = A4  + 1179648;       // 512*64*16  = 524288
    float* c16 = A5  + 524288;        // 2*24576    = 49152

    prep_w<<<dim3(488),  dim3(256), 0, stream>>>(w1, w2, w3, w4, w5, w6, wp);
    xinK  <<<dim3(1176), dim3(256), 0, stream>>>(x, A0);

    //     WIN CIN CO  NCO CPB PPL POOL           grid
    convU<14,  3, 16, 4,  1, 3, 0><<<dim3(512, 1), dim3(256), 0, stream>>>(A0, A1, wp + 0,     b1);
    convU<12, 16, 32, 4,  1, 2, 0><<<dim3(512, 2), dim3(256), 0, stream>>>(A1, A2, wp + 432,   b2);
    convU<10, 32, 32, 4,  1, 1, 0><<<dim3(512, 2), dim3(256), 0, stream>>>(A2, A3, wp + 5040,  b3);
    convU< 8, 32, 64, 8,  1, 1, 0><<<dim3(512, 2), dim3(256), 0, stream>>>(A3, A4, wp + 14256, b4);
    convU< 6, 64, 64, 4,  4, 1, 0><<<dim3(128, 4), dim3(256), 0, stream>>>(A4, A5, wp + 32688, b5);
    convU< 4, 64, 96, 6, 16, 1, 1><<<dim3( 32, 4), dim3(256), 0, stream>>>(A5, c16, wp + 69552, b6);

    slice_apply4<<<dim3(2 * HW1K / 4 / 256), dim3(256), 0, stream>>>(x, c16, out);

    (void)in_sizes; (void)n_in; (void)out_size; (void)ws_size;
}

// Round 13
// 94.881 us; speedup vs baseline: 2.6856x; 2.0025x over previous
//
#include <hip/hip_runtime.h>
#include <hip/hip_bf16.h>

#define HW1K  1048576    // 1024*1024

typedef float  f4    __attribute__((ext_vector_type(4)));
typedef float  f32x4 __attribute__((ext_vector_type(4)));
typedef short  s16x8 __attribute__((ext_vector_type(8)));   // MFMA bf16 frag (8 bf16)
typedef unsigned short u16x8 __attribute__((ext_vector_type(8)));

__device__ __forceinline__ float bf2f(unsigned short u) {
    unsigned int b = ((unsigned int)u) << 16;
    return __builtin_bit_cast(float, b);
}
// split x = hi + lo (both bf16, truncated): residual ~2^-16 relative.
__device__ __forceinline__ void fsplit(float x, unsigned short& h, unsigned short& l) {
    unsigned int xb = __builtin_bit_cast(unsigned int, x);
    h = (unsigned short)(xb >> 16);
    float fh = __builtin_bit_cast(float, xb & 0xffff0000u);
    float r = x - fh;
    l = (unsigned short)(__builtin_bit_cast(unsigned int, r) >> 16);
}

// ---------------------------------------------------------------------------
// Weight prep for MFMA layers L2..L6: OIHW fp32 -> W[co][Kp] bf16 hi/lo with
// k = kk*CIN + ci (kk = ky*3+kx). Kp padded to x32 (pad -> ZERO, so padded-K
// MFMA terms vanish). Ranges (shorts): W2@0 (32x160) W3@5120 (32x288)
// W4@14336 (64x288) W5@32768 (64x576) W6@69632 (96x576); total 124928.
__global__ __launch_bounds__(256)
void prep_wM(const float* __restrict__ w2, const float* __restrict__ w3,
             const float* __restrict__ w4, const float* __restrict__ w5,
             const float* __restrict__ w6,
             unsigned short* __restrict__ Wh, unsigned short* __restrict__ Wl) {
    int i = blockIdx.x * 256 + threadIdx.x;
    if (i >= 124928) return;
    const float* src; int base, cin, kp_;
    if      (i < 5120)  { src = w2; base = 0;     cin = 16; kp_ = 160; }
    else if (i < 14336) { src = w3; base = 5120;  cin = 32; kp_ = 288; }
    else if (i < 32768) { src = w4; base = 14336; cin = 32; kp_ = 288; }
    else if (i < 69632) { src = w5; base = 32768; cin = 64; kp_ = 576; }
    else                { src = w6; base = 69632; cin = 64; kp_ = 576; }
    int r  = i - base;
    int co = r / kp_;
    int kp = r % kp_;
    int kk = kp / cin;
    int ci = kp % cin;
    float v = (kk < 9) ? src[(co * cin + ci) * 9 + kk] : 0.0f;
    unsigned short h, l; fsplit(v, h, l);
    Wh[i] = h; Wl[i] = l;
}

// ---------------------------------------------------------------------------
// xin: A0[cell][c][196] fp32 = 14x14 cone of the exact 4x bilinear downsample.
__global__ __launch_bounds__(256)
void xinK(const float* __restrict__ x, float* __restrict__ A0) {
    int idx = blockIdx.x * 256 + threadIdx.x;
    if (idx >= 512 * 588) return;
    int cell = idx / 588, r = idx % 588;
    int c = r / 196, t = r % 196;
    int xi = t % 14, yi = t / 14;
    int b = cell >> 8, gy = (cell >> 4) & 15, gx = cell & 15;
    int ya = 16 * gy + 1 + yi, xa = 16 * gx + 1 + xi;
    const float* p = x + ((size_t)(b * 3 + c)) * HW1K + (4 * ya + 1) * 1024 + (4 * xa + 1);
    A0[idx] = 0.25f * (p[0] + p[1] + p[1024] + p[1025]);
}

// ---------------------------------------------------------------------------
// conv1 (VALU; CIN=3, K=27 too small for MFMA): block = cell, wave-uniform co
// (s_load weights from raw OIHW), lanes = px. Output bf16 hi/lo [cell][144][16].
__global__ __launch_bounds__(256)
void conv1M(const float* __restrict__ A0, const float* __restrict__ w1,
            const float* __restrict__ b1,
            unsigned short* __restrict__ Oh, unsigned short* __restrict__ Ol) {
    __shared__ float s[592];
    const int cell = blockIdx.x;
    for (int i = threadIdx.x; i < 588; i += 256)
        s[i] = A0[(size_t)cell * 588 + i];
    __syncthreads();

    const int wid  = __builtin_amdgcn_readfirstlane(threadIdx.x >> 6);
    const int lane = threadIdx.x & 63;
    const int co0  = wid * 4;                      // wave-uniform

    float acc[3][4]; int pxs[3], pb[3];
    #pragma unroll
    for (int t = 0; t < 3; ++t) {
        int px = lane + t * 64; if (px > 143) px = 143;
        pxs[t] = px;
        pb[t]  = (px / 12) * 14 + (px % 12);
        #pragma unroll
        for (int j = 0; j < 4; ++j) acc[t][j] = b1[co0 + j];
    }
    for (int ci = 0; ci < 3; ++ci) {
        #pragma unroll
        for (int k = 0; k < 9; ++k) {
            float w[4];
            #pragma unroll
            for (int j = 0; j < 4; ++j)
                w[j] = w1[((co0 + j) * 3 + ci) * 9 + k];   // s_load
            const int ko = (k / 3) * 14 + (k % 3);
            #pragma unroll
            for (int t = 0; t < 3; ++t) {
                float a = s[ci * 196 + pb[t] + ko];
                #pragma unroll
                for (int j = 0; j < 4; ++j) acc[t][j] = fmaf(w[j], a, acc[t][j]);
            }
        }
    }
    #pragma unroll
    for (int t = 0; t < 3; ++t)
        #pragma unroll
        for (int j = 0; j < 4; ++j) {
            float v = fmaxf(acc[t][j], 0.0f);
            unsigned short h, l; fsplit(v, h, l);
            size_t oi = ((size_t)cell * 144 + pxs[t]) * 16 + co0 + j;
            Oh[oi] = h; Ol[oi] = l;                // clamp-dups write same value
        }
}

// ---------------------------------------------------------------------------
// MFMA conv layer (split-bf16, 3 MFMAs per K-step into 3 accs).
// Block = 1 cell, 4 waves; wave handles (Mtile,Ntile) pairs round-robin.
// A: LDS act tile [ROWS][CINP] bf16 hi/lo (CINP=CIN+8 pad: 2-way-free banks);
//    frag = contiguous ds_read_b128 at ((pxr+ky)*WIN+pxc+kx)*CINP + ci0.
// B: global W[co][KP] bf16 (contiguous 16B per frag, L2-resident).
// Layout assumption: A row=lane&15, k=8*(lane>>4)+j; B col=lane&15 same k;
// D col=lane&15, row=4*(lane>>4)+reg  [m89-verified C/D].
template <int WIN, int CIN, int COUT, int KP>
__global__ __launch_bounds__(256)
void convM(const unsigned short* __restrict__ Ah, const unsigned short* __restrict__ Al,
           const unsigned short* __restrict__ Wh, const unsigned short* __restrict__ Wl,
           const float* __restrict__ bias,
           unsigned short* __restrict__ Oh, unsigned short* __restrict__ Ol) {
    constexpr int WOUT = WIN - 2;
    constexpr int NPX  = WOUT * WOUT;
    constexpr int NPIN = WIN * WIN;
    constexpr int CINP = CIN + 8;
    constexpr int ROWS = NPIN + 16;       // margin rows (zeroed) for K-pad reads
    constexpr int MT   = (NPX + 15) / 16;
    constexpr int NT   = COUT / 16;
    constexpr int PAIRS = MT * NT;

    __shared__ __align__(16) unsigned short sH[ROWS * CINP];
    __shared__ __align__(16) unsigned short sL[ROWS * CINP];

    const int cell = blockIdx.x;

    for (int i = threadIdx.x; i < NPIN * CIN / 8; i += 256) {
        int px = i / (CIN / 8), c8 = i % (CIN / 8);
        *(u16x8*)(&sH[px * CINP + c8 * 8]) =
            *(const u16x8*)(&Ah[((size_t)cell * NPIN + px) * CIN + c8 * 8]);
        *(u16x8*)(&sL[px * CINP + c8 * 8]) =
            *(const u16x8*)(&Al[((size_t)cell * NPIN + px) * CIN + c8 * 8]);
    }
    for (int i = threadIdx.x; i < 16 * CINP; i += 256) {   // zero margin (NaN guard)
        sH[NPIN * CINP + i] = 0; sL[NPIN * CINP + i] = 0;
    }
    __syncthreads();

    const int wid  = threadIdx.x >> 6;
    const int lane = threadIdx.x & 63;
    const int m    = lane & 15;
    const int g    = lane >> 4;

    #pragma unroll 1
    for (int p = wid; p < PAIRS; p += 4) {
        const int mt0 = (p / NT) * 16;
        const int nt0 = (p % NT) * 16;
        int px = mt0 + m; if (px > NPX - 1) px = NPX - 1;
        const int pbase = (px / WOUT) * WIN + (px % WOUT);
        const int co = nt0 + m;
        const unsigned short* wbh = Wh + (size_t)co * KP + 8 * g;
        const unsigned short* wbl = Wl + (size_t)co * KP + 8 * g;

        f32x4 aHH = {0,0,0,0}, aHL = {0,0,0,0}, aLH = {0,0,0,0};
        for (int k0 = 0; k0 < KP; k0 += 32) {
            const int k   = k0 + 8 * g;
            const int kk  = k / CIN;            // power-of-2 shifts
            const int ci0 = k % CIN;
            const int aoff = (pbase + (kk / 3) * WIN + (kk % 3)) * CINP + ci0;
            s16x8 avh = *(const s16x8*)(&sH[aoff]);
            s16x8 avl = *(const s16x8*)(&sL[aoff]);
            s16x8 bvh = *(const s16x8*)(wbh + k0);
            s16x8 bvl = *(const s16x8*)(wbl + k0);
            aHH = __builtin_amdgcn_mfma_f32_16x16x32_bf16(avh, bvh, aHH, 0, 0, 0);
            aHL = __builtin_amdgcn_mfma_f32_16x16x32_bf16(avh, bvl, aHL, 0, 0, 0);
            aLH = __builtin_amdgcn_mfma_f32_16x16x32_bf16(avl, bvh, aLH, 0, 0, 0);
        }
        const float bv = bias[co];
        #pragma unroll
        for (int j = 0; j < 4; ++j) {
            int opx = mt0 + g * 4 + j;
            if (opx < NPX) {
                float v = aHH[j] + aHL[j] + aLH[j] + bv;
                v = fmaxf(v, 0.0f);
                unsigned short h, l; fsplit(v, h, l);
                size_t oi = ((size_t)cell * NPX + opx) * COUT + co;
                Oh[oi] = h; Ol[oi] = l;
            }
        }
    }
}

// ---------------------------------------------------------------------------
// pool5: fold the (linear, pre-conv6) 2x2 pooling into the L6 GEMM's A:
// abar[cell][kp=kk*64+ci] = 0.25 * sum_{dr,dc} t5[(kk/3+dr)*4 + kk%3+dc][ci].
__global__ __launch_bounds__(256)
void pool5(const unsigned short* __restrict__ A5h, const unsigned short* __restrict__ A5l,
           unsigned short* __restrict__ Bh, unsigned short* __restrict__ Bl) {
    int idx = blockIdx.x * 256 + threadIdx.x;
    if (idx >= 512 * 576) return;
    int cell = idx / 576, kp = idx % 576;
    int kk = kp >> 6, ci = kp & 63;
    int ky = kk / 3, kx = kk % 3;
    float v = 0.0f;
    #pragma unroll
    for (int dr = 0; dr < 2; ++dr)
        #pragma unroll
        for (int dc = 0; dc < 2; ++dc) {
            int px = (ky + dr) * 4 + (kx + dc);
            size_t ai = ((size_t)cell * 16 + px) * 64 + ci;
            v += bf2f(A5h[ai]) + bf2f(A5l[ai]);
        }
    v *= 0.25f;
    unsigned short h, l; fsplit(v, h, l);
    Bh[idx] = h; Bl[idx] = l;
}

// ---------------------------------------------------------------------------
// L6 as GEMM: M=512 cells, K=576, N=96. 1-wave blocks, grid (32 Mtiles, 6 Ntiles).
// Writes c16[b][gyx][d][p] fp32 (no ReLU), bias folded.
__global__ __launch_bounds__(64)
void gemm6(const unsigned short* __restrict__ Bh, const unsigned short* __restrict__ Bl,
           const unsigned short* __restrict__ W6h, const unsigned short* __restrict__ W6l,
           const float* __restrict__ b6, float* __restrict__ c16) {
    const int cell0 = blockIdx.x * 16;
    const int co0   = blockIdx.y * 16;
    const int lane  = threadIdx.x;
    const int m = lane & 15, g = lane >> 4;

    const unsigned short* pah = Bh  + (size_t)(cell0 + m) * 576 + 8 * g;
    const unsigned short* pal = Bl  + (size_t)(cell0 + m) * 576 + 8 * g;
    const unsigned short* pbh = W6h + (size_t)(co0 + m) * 576 + 8 * g;
    const unsigned short* pbl = W6l + (size_t)(co0 + m) * 576 + 8 * g;

    f32x4 aHH = {0,0,0,0}, aHL = {0,0,0,0}, aLH = {0,0,0,0};
    for (int k0 = 0; k0 < 576; k0 += 32) {
        s16x8 avh = *(const s16x8*)(pah + k0);
        s16x8 avl = *(const s16x8*)(pal + k0);
        s16x8 bvh = *(const s16x8*)(pbh + k0);
        s16x8 bvl = *(const s16x8*)(pbl + k0);
        aHH = __builtin_amdgcn_mfma_f32_16x16x32_bf16(avh, bvh, aHH, 0, 0, 0);
        aHL = __builtin_amdgcn_mfma_f32_16x16x32_bf16(avh, bvl, aHL, 0, 0, 0);
        aLH = __builtin_amdgcn_mfma_f32_16x16x32_bf16(avl, bvh, aLH, 0, 0, 0);
    }
    const int co = co0 + m;
    const float bv = b6[co];
    #pragma unroll
    for (int j = 0; j < 4; ++j) {
        int cell = cell0 + g * 4 + j;
        float v = aHH[j] + aHL[j] + aLH[j] + bv;
        int b = cell >> 8, gyx = cell & 255;
        c16[(size_t)b * 24576 + (gyx * 8 + (co & 7)) * 12 + (co >> 3)] = v;
    }
}

// ---------------------------------------------------------------------------
// Fused guide + trilinear slice + affine + clip; 4 px per thread (float4).
__global__ __launch_bounds__(256)
void slice_apply4(const float* __restrict__ x, const float* __restrict__ c16,
                  float* __restrict__ out) {
    int t = blockIdx.x * 256 + threadIdx.x;
    int po4 = t * 4;
    int b   = po4 >> 20;
    int po  = po4 & (HW1K - 1);
    int py  = po >> 10;
    int px0 = po & 1023;

    const float* xb = x + (size_t)b * 3 * HW1K;
    f4 rv  = *(const f4*)(xb + po);
    f4 gv  = *(const f4*)(xb + HW1K + po);
    f4 bv  = *(const f4*)(xb + 2 * HW1K + po);

    float ysf = (float)py * (15.0f / 1023.0f);
    int y0 = (int)floorf(ysf); int y1 = min(y0 + 1, 15);
    float wy = ysf - (float)y0;

    const float* gb = c16 + (size_t)b * 24576;
    f4 outv[3];

    #pragma unroll
    for (int s = 0; s < 4; ++s) {
        float r  = rv[s], g = gv[s], bl = bv[s];
        int   px = px0 + s;

        float gd = fminf(fmaxf(0.299f * r + 0.587f * g + 0.114f * bl, 0.0f), 1.0f);

        float xsf = (float)px * (15.0f / 1023.0f);
        int x0 = (int)floorf(xsf); int x1 = min(x0 + 1, 15);
        float wx = xsf - (float)x0;

        float d  = gd * 7.0f;
        int d0 = (int)floorf(d); d0 = max(0, min(d0, 7));
        int d1 = min(d0 + 1, 7);
        float wd = fminf(fmaxf(d - (float)d0, 0.0f), 1.0f);

        float co[12];
        #pragma unroll
        for (int p = 0; p < 12; ++p) co[p] = 0.0f;

        #pragma unroll
        for (int cy = 0; cy < 2; ++cy) {
            int   yy  = cy ? y1 : y0;
            float wyf = cy ? wy : 1.0f - wy;
            #pragma unroll
            for (int cx = 0; cx < 2; ++cx) {
                int   xx  = cx ? x1 : x0;
                float wyx = wyf * (cx ? wx : 1.0f - wx);
                const float* g0 = gb + ((yy * 16 + xx) * 8 + d0) * 12;
                const float* g1 = gb + ((yy * 16 + xx) * 8 + d1) * 12;
                float wA = wyx * (1.0f - wd), wB = wyx * wd;
                #pragma unroll
                for (int p = 0; p < 12; ++p) co[p] += wA * g0[p] + wB * g1[p];
            }
        }

        #pragma unroll
        for (int i = 0; i < 3; ++i) {
            float v = co[i * 4 + 0] * r + co[i * 4 + 1] * g + co[i * 4 + 2] * bl + co[i * 4 + 3];
            outv[i][s] = fminf(fmaxf(v, 0.0f), 1.0f);
        }
    }

    float* ob = out + (size_t)b * 3 * HW1K;
    #pragma unroll
    for (int i = 0; i < 3; ++i)
        *(f4*)(ob + i * HW1K + po) = outv[i];
}

// ---------------------------------------------------------------------------
extern "C" void kernel_launch(void* const* d_in, const int* in_sizes, int n_in,
                              void* d_out, int out_size, void* d_ws, size_t ws_size,
                              hipStream_t stream) {
    const float* x  = (const float*)d_in[0];
    const float* w1 = (const float*)d_in[1];  const float* b1 = (const float*)d_in[2];
    const float* w2 = (const float*)d_in[3];  const float* b2 = (const float*)d_in[4];
    const float* w3 = (const float*)d_in[5];  const float* b3 = (const float*)d_in[6];
    const float* w4 = (const float*)d_in[7];  const float* b4 = (const float*)d_in[8];
    const float* w5 = (const float*)d_in[9];  const float* b5 = (const float*)d_in[10];
    const float* w6 = (const float*)d_in[11]; const float* b6 = (const float*)d_in[12];
    float* out = (float*)d_out;

    // Workspace layout (byte offsets, all 16B-aligned):
    char* w = (char*)d_ws;
    unsigned short* Wh  = (unsigned short*)w;              w += 124928 * 2;
    unsigned short* Wl  = (unsigned short*)w;              w += 124928 * 2;
    float*          A0  = (float*)w;                       w += 512 * 588 * 4;
    unsigned short* A1h = (unsigned short*)w;              w += 512 * 144 * 16 * 2;
    unsigned short* A1l = (unsigned short*)w;              w += 512 * 144 * 16 * 2;
    unsigned short* A2h = (unsigned short*)w;              w += 512 * 100 * 32 * 2;
    unsigned short* A2l = (unsigned short*)w;              w += 512 * 100 * 32 * 2;
    unsigned short* A3h = (unsigned short*)w;              w += 512 * 64 * 32 * 2;
    unsigned short* A3l = (unsigned short*)w;              w += 512 * 64 * 32 * 2;
    unsigned short* A4h = (unsigned short*)w;              w += 512 * 36 * 64 * 2;
    unsigned short* A4l = (unsigned short*)w;              w += 512 * 36 * 64 * 2;
    unsigned short* A5h = (unsigned short*)w;              w += 512 * 16 * 64 * 2;
    unsigned short* A5l = (unsigned short*)w;              w += 512 * 16 * 64 * 2;
    unsigned short* P6h = (unsigned short*)w;              w += 512 * 576 * 2;
    unsigned short* P6l = (unsigned short*)w;              w += 512 * 576 * 2;
    float*          c16 = (float*)w;

    prep_wM<<<dim3(489),  dim3(256), 0, stream>>>(w2, w3, w4, w5, w6, Wh, Wl);
    xinK   <<<dim3(1176), dim3(256), 0, stream>>>(x, A0);
    conv1M <<<dim3(512),  dim3(256), 0, stream>>>(A0, w1, b1, A1h, A1l);

    convM<12, 16, 32, 160><<<dim3(512), dim3(256), 0, stream>>>(A1h, A1l, Wh + 0,     Wl + 0,     b2, A2h, A2l);
    convM<10, 32, 32, 288><<<dim3(512), dim3(256), 0, stream>>>(A2h, A2l, Wh + 5120,  Wl + 5120,  b3, A3h, A3l);
    convM< 8, 32, 64, 288><<<dim3(512), dim3(256), 0, stream>>>(A3h, A3l, Wh + 14336, Wl + 14336, b4, A4h, A4l);
    convM< 6, 64, 64, 576><<<dim3(512), dim3(256), 0, stream>>>(A4h, A4l, Wh + 32768, Wl + 32768, b5, A5h, A5l);

    pool5<<<dim3(1152), dim3(256), 0, stream>>>(A5h, A5l, P6h, P6l);
    gemm6<<<dim3(32, 6), dim3(64), 0, stream>>>(P6h, P6l, Wh + 69632, Wl + 69632, b6, c16);

    slice_apply4<<<dim3(2 * HW1K / 4 / 256), dim3(256), 0, stream>>>(x, c16, out);

    (void)in_sizes; (void)n_in; (void)out_size; (void)ws_size;
}

// Round 14
// 75.356 us; speedup vs baseline: 3.3814x; 1.2591x over previous
//
#include <hip/hip_runtime.h>
#include <hip/hip_bf16.h>

#define HW1K  1048576    // 1024*1024

typedef float  f4    __attribute__((ext_vector_type(4)));
typedef float  f32x4 __attribute__((ext_vector_type(4)));
typedef short  s16x8 __attribute__((ext_vector_type(8)));   // MFMA bf16 frag
typedef unsigned short u16x8 __attribute__((ext_vector_type(8)));

__device__ __forceinline__ float bf2f(unsigned short u) {
    unsigned int b = ((unsigned int)u) << 16;
    return __builtin_bit_cast(float, b);
}
// split x = hi + lo (both bf16, truncated): residual ~2^-16 relative.
__device__ __forceinline__ void fsplit(float x, unsigned short& h, unsigned short& l) {
    unsigned int xb = __builtin_bit_cast(unsigned int, x);
    h = (unsigned short)(xb >> 16);
    float fh = __builtin_bit_cast(float, xb & 0xffff0000u);
    float r = x - fh;
    l = (unsigned short)(__builtin_bit_cast(unsigned int, r) >> 16);
}

// ---------------------------------------------------------------------------
// Weight prep (L2..L6): OIHW fp32 -> W[co][Kp] bf16 hi/lo, k = kk*CIN+ci,
// Kp padded x32 with ZERO. Ranges (shorts): W2@0(32x160) W3@5120(32x288)
// W4@14336(64x288) W5@32768(64x576) W6@69632(96x576); total 124928.
__global__ __launch_bounds__(256)
void prep_wM(const float* __restrict__ w2, const float* __restrict__ w3,
             const float* __restrict__ w4, const float* __restrict__ w5,
             const float* __restrict__ w6,
             unsigned short* __restrict__ Wh, unsigned short* __restrict__ Wl) {
    int i = blockIdx.x * 256 + threadIdx.x;
    if (i >= 124928) return;
    const float* src; int base, cin, kp_;
    if      (i < 5120)  { src = w2; base = 0;     cin = 16; kp_ = 160; }
    else if (i < 14336) { src = w3; base = 5120;  cin = 32; kp_ = 288; }
    else if (i < 32768) { src = w4; base = 14336; cin = 32; kp_ = 288; }
    else if (i < 69632) { src = w5; base = 32768; cin = 64; kp_ = 576; }
    else                { src = w6; base = 69632; cin = 64; kp_ = 576; }
    int r  = i - base;
    int co = r / kp_;
    int kp = r % kp_;
    int kk = kp / cin;
    int ci = kp % cin;
    float v = (kk < 9) ? src[(co * cin + ci) * 9 + kk] : 0.0f;
    unsigned short h, l; fsplit(v, h, l);
    Wh[i] = h; Wl[i] = l;
}

// ---------------------------------------------------------------------------
// One MFMA conv layer, LDS(or global) -> LDS(or global), called inside the
// fused kernel. In: [px][CINP=CIN+8] bf16 hi/lo (pads give 16B-aligned
// contiguous A-frags = 1 ds_read_b128). B: global W[co][KP] bf16. Split-bf16:
// 3 MFMAs (HH,HL,LH) per K-step. D: col=lane&15 (=co), row=4*(lane>>4)+j.
template <int WIN, int CIN, int COUT, int KP, int SO>
__device__ __forceinline__ void layerM(const unsigned short* sH, const unsigned short* sL,
                                       unsigned short* dH, unsigned short* dL,
                                       const unsigned short* __restrict__ Wh,
                                       const unsigned short* __restrict__ Wl,
                                       const float* __restrict__ bias) {
    constexpr int WOUT = WIN - 2;
    constexpr int NPX  = WOUT * WOUT;
    constexpr int CINP = CIN + 8;
    constexpr int MT   = (NPX + 15) / 16;
    constexpr int NT   = COUT / 16;
    constexpr int PAIRS = MT * NT;

    const int wid  = threadIdx.x >> 6;
    const int lane = threadIdx.x & 63;
    const int m    = lane & 15;
    const int g    = lane >> 4;

    #pragma unroll 1
    for (int p = wid; p < PAIRS; p += 4) {
        const int mt0 = (p / NT) * 16;
        const int nt0 = (p % NT) * 16;
        int px = mt0 + m; if (px > NPX - 1) px = NPX - 1;
        const int pbase = (px / WOUT) * WIN + (px % WOUT);
        const int co = nt0 + m;
        const unsigned short* wbh = Wh + (size_t)co * KP + 8 * g;
        const unsigned short* wbl = Wl + (size_t)co * KP + 8 * g;

        f32x4 aHH = {0,0,0,0}, aHL = {0,0,0,0}, aLH = {0,0,0,0};
        for (int k0 = 0; k0 < KP; k0 += 32) {
            const int k   = k0 + 8 * g;
            const int kk  = k / CIN;
            const int ci0 = k % CIN;
            const int aoff = (pbase + (kk / 3) * WIN + (kk % 3)) * CINP + ci0;
            s16x8 avh = *(const s16x8*)(&sH[aoff]);
            s16x8 avl = *(const s16x8*)(&sL[aoff]);
            s16x8 bvh = *(const s16x8*)(wbh + k0);
            s16x8 bvl = *(const s16x8*)(wbl + k0);
            aHH = __builtin_amdgcn_mfma_f32_16x16x32_bf16(avh, bvh, aHH, 0, 0, 0);
            aHL = __builtin_amdgcn_mfma_f32_16x16x32_bf16(avh, bvl, aHL, 0, 0, 0);
            aLH = __builtin_amdgcn_mfma_f32_16x16x32_bf16(avl, bvh, aLH, 0, 0, 0);
        }
        const float bv = bias[co];
        #pragma unroll
        for (int j = 0; j < 4; ++j) {
            int opx = mt0 + g * 4 + j;
            if (opx < NPX) {
                float v = aHH[j] + aHL[j] + aLH[j] + bv;
                v = fmaxf(v, 0.0f);
                unsigned short h, l; fsplit(v, h, l);
                dH[opx * SO + co] = h;
                dL[opx * SO + co] = l;
            }
        }
    }
}

// ---------------------------------------------------------------------------
// Fused cone + conv1(VALU) + conv2..conv5(MFMA, LDS ping-pong) -> A5 global.
// Block = cell (512 blocks, 256 thr). LDS ~34KB.
__global__ __launch_bounds__(256)
void fusedM(const float* __restrict__ x, const float* __restrict__ w1,
            const float* __restrict__ b1,
            const unsigned short* __restrict__ Wh, const unsigned short* __restrict__ Wl,
            const float* __restrict__ b2, const float* __restrict__ b3,
            const float* __restrict__ b4, const float* __restrict__ b5,
            unsigned short* __restrict__ A5h, unsigned short* __restrict__ A5l) {
    __shared__ float sC[592];                       // cone [ci][196] fp32
    __shared__ __align__(16) unsigned short AH[3840], AL[3840];  // t1 [144+16][24] / t3 [64][40]
    __shared__ __align__(16) unsigned short BH[4000], BL[4000];  // t2 [100][40]    / t4 [36][72]

    const int cell = blockIdx.x;
    const int b = cell >> 8, gy = (cell >> 4) & 15, gx = cell & 15;

    // cone: sC[c][196]; xlow[y][x] = avg of x rows 4y+1..4y+2, cols 4x+1..4x+2.
    // Coords in [1,254]: zero-padding never triggers.
    for (int i = threadIdx.x; i < 588; i += 256) {
        int c = i / 196, t = i % 196;
        int xi = t % 14, yi = t / 14;
        int ya = 16 * gy + 1 + yi, xa = 16 * gx + 1 + xi;
        const float* p = x + ((size_t)(b * 3 + c)) * HW1K + (4 * ya + 1) * 1024 + (4 * xa + 1);
        sC[i] = 0.25f * (p[0] + p[1] + p[1024] + p[1025]);
    }
    // zero t1 margin rows 144..159 (read by L2's kk=9 zero-weight taps)
    for (int i = threadIdx.x; i < 384; i += 256) { AH[3456 + i] = 0; AL[3456 + i] = 0; }
    __syncthreads();

    // conv1 (VALU): wave=4 co, lanes=px (3 strips). out t1 [px][24] hi/lo.
    {
        const int wid  = __builtin_amdgcn_readfirstlane(threadIdx.x >> 6);
        const int lane = threadIdx.x & 63;
        const int co0  = wid * 4;
        float acc[3][4]; int pxs[3], pb[3];
        #pragma unroll
        for (int t = 0; t < 3; ++t) {
            int px = lane + t * 64; if (px > 143) px = 143;
            pxs[t] = px; pb[t] = (px / 12) * 14 + (px % 12);
            #pragma unroll
            for (int j = 0; j < 4; ++j) acc[t][j] = b1[co0 + j];
        }
        for (int ci = 0; ci < 3; ++ci)
            #pragma unroll
            for (int k = 0; k < 9; ++k) {
                float w[4];
                #pragma unroll
                for (int j = 0; j < 4; ++j) w[j] = w1[((co0 + j) * 3 + ci) * 9 + k];
                const int ko = (k / 3) * 14 + (k % 3);
                #pragma unroll
                for (int t = 0; t < 3; ++t) {
                    float a = sC[ci * 196 + pb[t] + ko];
                    #pragma unroll
                    for (int j = 0; j < 4; ++j) acc[t][j] = fmaf(w[j], a, acc[t][j]);
                }
            }
        #pragma unroll
        for (int t = 0; t < 3; ++t)
            #pragma unroll
            for (int j = 0; j < 4; ++j) {
                float v = fmaxf(acc[t][j], 0.0f);
                unsigned short h, l; fsplit(v, h, l);
                AH[pxs[t] * 24 + co0 + j] = h;
                AL[pxs[t] * 24 + co0 + j] = l;
            }
    }
    __syncthreads();

    layerM<12, 16, 32, 160, 40>(AH, AL, BH, BL, Wh + 0,     Wl + 0,     b2);
    __syncthreads();
    layerM<10, 32, 32, 288, 40>(BH, BL, AH, AL, Wh + 5120,  Wl + 5120,  b3);
    __syncthreads();
    layerM< 8, 32, 64, 288, 72>(AH, AL, BH, BL, Wh + 14336, Wl + 14336, b4);
    __syncthreads();
    layerM< 6, 64, 64, 576, 64>(BH, BL, A5h + (size_t)cell * 1024, A5l + (size_t)cell * 1024,
                                Wh + 32768, Wl + 32768, b5);
}

// ---------------------------------------------------------------------------
// pool5: fold 2x2 pooling into L6's A: abar[cell][kk*64+ci].
__global__ __launch_bounds__(256)
void pool5(const unsigned short* __restrict__ A5h, const unsigned short* __restrict__ A5l,
           unsigned short* __restrict__ Bh, unsigned short* __restrict__ Bl) {
    int idx = blockIdx.x * 256 + threadIdx.x;
    if (idx >= 512 * 576) return;
    int cell = idx / 576, kp = idx % 576;
    int kk = kp >> 6, ci = kp & 63;
    int ky = kk / 3, kx = kk % 3;
    float v = 0.0f;
    #pragma unroll
    for (int dr = 0; dr < 2; ++dr)
        #pragma unroll
        for (int dc = 0; dc < 2; ++dc) {
            int px = (ky + dr) * 4 + (kx + dc);
            size_t ai = ((size_t)cell * 16 + px) * 64 + ci;
            v += bf2f(A5h[ai]) + bf2f(A5l[ai]);
        }
    v *= 0.25f;
    unsigned short h, l; fsplit(v, h, l);
    Bh[idx] = h; Bl[idx] = l;
}

// ---------------------------------------------------------------------------
// L6 as GEMM: M=512 cells, K=576, N=96; 1-wave blocks, grid (32, 6).
__global__ __launch_bounds__(64)
void gemm6(const unsigned short* __restrict__ Bh, const unsigned short* __restrict__ Bl,
           const unsigned short* __restrict__ W6h, const unsigned short* __restrict__ W6l,
           const float* __restrict__ b6, float* __restrict__ c16) {
    const int cell0 = blockIdx.x * 16;
    const int co0   = blockIdx.y * 16;
    const int lane  = threadIdx.x;
    const int m = lane & 15, g = lane >> 4;

    const unsigned short* pah = Bh  + (size_t)(cell0 + m) * 576 + 8 * g;
    const unsigned short* pal = Bl  + (size_t)(cell0 + m) * 576 + 8 * g;
    const unsigned short* pbh = W6h + (size_t)(co0 + m) * 576 + 8 * g;
    const unsigned short* pbl = W6l + (size_t)(co0 + m) * 576 + 8 * g;

    f32x4 aHH = {0,0,0,0}, aHL = {0,0,0,0}, aLH = {0,0,0,0};
    for (int k0 = 0; k0 < 576; k0 += 32) {
        s16x8 avh = *(const s16x8*)(pah + k0);
        s16x8 avl = *(const s16x8*)(pal + k0);
        s16x8 bvh = *(const s16x8*)(pbh + k0);
        s16x8 bvl = *(const s16x8*)(pbl + k0);
        aHH = __builtin_amdgcn_mfma_f32_16x16x32_bf16(avh, bvh, aHH, 0, 0, 0);
        aHL = __builtin_amdgcn_mfma_f32_16x16x32_bf16(avh, bvl, aHL, 0, 0, 0);
        aLH = __builtin_amdgcn_mfma_f32_16x16x32_bf16(avl, bvh, aLH, 0, 0, 0);
    }
    const int co = co0 + m;
    const float bv = b6[co];
    #pragma unroll
    for (int j = 0; j < 4; ++j) {
        int cell = cell0 + g * 4 + j;
        float v = aHH[j] + aHL[j] + aLH[j] + bv;
        int b = cell >> 8, gyx = cell & 255;
        c16[(size_t)b * 24576 + (gyx * 8 + (co & 7)) * 12 + (co >> 3)] = v;
    }
}

// ---------------------------------------------------------------------------
// Fused guide + trilinear slice + affine + clip; 4 px per thread.
__global__ __launch_bounds__(256)
void slice_apply4(const float* __restrict__ x, const float* __restrict__ c16,
                  float* __restrict__ out) {
    int t = blockIdx.x * 256 + threadIdx.x;
    int po4 = t * 4;
    int b   = po4 >> 20;
    int po  = po4 & (HW1K - 1);
    int py  = po >> 10;
    int px0 = po & 1023;

    const float* xb = x + (size_t)b * 3 * HW1K;
    f4 rv  = *(const f4*)(xb + po);
    f4 gv  = *(const f4*)(xb + HW1K + po);
    f4 bv  = *(const f4*)(xb + 2 * HW1K + po);

    float ysf = (float)py * (15.0f / 1023.0f);
    int y0 = (int)floorf(ysf); int y1 = min(y0 + 1, 15);
    float wy = ysf - (float)y0;

    const float* gb = c16 + (size_t)b * 24576;
    f4 outv[3];

    #pragma unroll
    for (int s = 0; s < 4; ++s) {
        float r  = rv[s], g = gv[s], bl = bv[s];
        int   px = px0 + s;

        float gd = fminf(fmaxf(0.299f * r + 0.587f * g + 0.114f * bl, 0.0f), 1.0f);

        float xsf = (float)px * (15.0f / 1023.0f);
        int x0 = (int)floorf(xsf); int x1 = min(x0 + 1, 15);
        float wx = xsf - (float)x0;

        float d  = gd * 7.0f;
        int d0 = (int)floorf(d); d0 = max(0, min(d0, 7));
        int d1 = min(d0 + 1, 7);
        float wd = fminf(fmaxf(d - (float)d0, 0.0f), 1.0f);

        float co[12];
        #pragma unroll
        for (int p = 0; p < 12; ++p) co[p] = 0.0f;

        #pragma unroll
        for (int cy = 0; cy < 2; ++cy) {
            int   yy  = cy ? y1 : y0;
            float wyf = cy ? wy : 1.0f - wy;
            #pragma unroll
            for (int cx = 0; cx < 2; ++cx) {
                int   xx  = cx ? x1 : x0;
                float wyx = wyf * (cx ? wx : 1.0f - wx);
                const float* g0 = gb + ((yy * 16 + xx) * 8 + d0) * 12;
                const float* g1 = gb + ((yy * 16 + xx) * 8 + d1) * 12;
                float wA = wyx * (1.0f - wd), wB = wyx * wd;
                #pragma unroll
                for (int p = 0; p < 12; ++p) co[p] += wA * g0[p] + wB * g1[p];
            }
        }

        #pragma unroll
        for (int i = 0; i < 3; ++i) {
            float v = co[i * 4 + 0] * r + co[i * 4 + 1] * g + co[i * 4 + 2] * bl + co[i * 4 + 3];
            outv[i][s] = fminf(fmaxf(v, 0.0f), 1.0f);
        }
    }

    float* ob = out + (size_t)b * 3 * HW1K;
    #pragma unroll
    for (int i = 0; i < 3; ++i)
        *(f4*)(ob + i * HW1K + po) = outv[i];
}

// ---------------------------------------------------------------------------
extern "C" void kernel_launch(void* const* d_in, const int* in_sizes, int n_in,
                              void* d_out, int out_size, void* d_ws, size_t ws_size,
                              hipStream_t stream) {
    const float* x  = (const float*)d_in[0];
    const float* w1 = (const float*)d_in[1];  const float* b1 = (const float*)d_in[2];
    const float* w2 = (const float*)d_in[3];  const float* b2 = (const float*)d_in[4];
    const float* w3 = (const float*)d_in[5];  const float* b3 = (const float*)d_in[6];
    const float* w4 = (const float*)d_in[7];  const float* b4 = (const float*)d_in[8];
    const float* w5 = (const float*)d_in[9];  const float* b5 = (const float*)d_in[10];
    const float* w6 = (const float*)d_in[11]; const float* b6 = (const float*)d_in[12];
    float* out = (float*)d_out;

    char* w = (char*)d_ws;
    unsigned short* Wh  = (unsigned short*)w;   w += 124928 * 2;
    unsigned short* Wl  = (unsigned short*)w;   w += 124928 * 2;
    unsigned short* A5h = (unsigned short*)w;   w += 512 * 1024 * 2;
    unsigned short* A5l = (unsigned short*)w;   w += 512 * 1024 * 2;
    unsigned short* P6h = (unsigned short*)w;   w += 512 * 576 * 2;
    unsigned short* P6l = (unsigned short*)w;   w += 512 * 576 * 2;
    float*          c16 = (float*)w;

    prep_wM<<<dim3(489),  dim3(256), 0, stream>>>(w2, w3, w4, w5, w6, Wh, Wl);
    fusedM <<<dim3(512),  dim3(256), 0, stream>>>(x, w1, b1, Wh, Wl, b2, b3, b4, b5, A5h, A5l);
    pool5  <<<dim3(1152), dim3(256), 0, stream>>>(A5h, A5l, P6h, P6l);
    gemm6  <<<dim3(32, 6), dim3(64), 0, stream>>>(P6h, P6l, Wh + 69632, Wl + 69632, b6, c16);
    slice_apply4<<<dim3(2 * HW1K / 4 / 256), dim3(256), 0, stream>>>(x, c16, out);

    (void)in_sizes; (void)n_in; (void)out_size; (void)ws_size;
}

// Round 15
// 66.547 us; speedup vs baseline: 3.8290x; 1.1324x over previous
//
#include <hip/hip_runtime.h>
#include <hip/hip_bf16.h>

#define HW1K  1048576    // 1024*1024

typedef float  f4    __attribute__((ext_vector_type(4)));
typedef float  f32x4 __attribute__((ext_vector_type(4)));
typedef short  s16x8 __attribute__((ext_vector_type(8)));   // MFMA bf16 frag
typedef unsigned short u16x8 __attribute__((ext_vector_type(8)));

__device__ __forceinline__ float bf2f(unsigned short u) {
    unsigned int b = ((unsigned int)u) << 16;
    return __builtin_bit_cast(float, b);
}
// split x = hi + lo (both bf16, truncated): residual ~2^-16 relative.
__device__ __forceinline__ void fsplit(float x, unsigned short& h, unsigned short& l) {
    unsigned int xb = __builtin_bit_cast(unsigned int, x);
    h = (unsigned short)(xb >> 16);
    float fh = __builtin_bit_cast(float, xb & 0xffff0000u);
    float r = x - fh;
    l = (unsigned short)(__builtin_bit_cast(unsigned int, r) >> 16);
}

// ---------------------------------------------------------------------------
// Weight prep (L2..L6): OIHW fp32 -> W[co][Kp] bf16 hi/lo, k = kk*CIN+ci,
// Kp padded x32 with ZERO. Ranges (shorts): W2@0(32x160) W3@5120(32x288)
// W4@14336(64x288) W5@32768(64x576) W6@69632(96x576); total 124928.
__global__ __launch_bounds__(256)
void prep_wM(const float* __restrict__ w2, const float* __restrict__ w3,
             const float* __restrict__ w4, const float* __restrict__ w5,
             const float* __restrict__ w6,
             unsigned short* __restrict__ Wh, unsigned short* __restrict__ Wl) {
    int i = blockIdx.x * 256 + threadIdx.x;
    if (i >= 124928) return;
    const float* src; int base, cin, kp_;
    if      (i < 5120)  { src = w2; base = 0;     cin = 16; kp_ = 160; }
    else if (i < 14336) { src = w3; base = 5120;  cin = 32; kp_ = 288; }
    else if (i < 32768) { src = w4; base = 14336; cin = 32; kp_ = 288; }
    else if (i < 69632) { src = w5; base = 32768; cin = 64; kp_ = 576; }
    else                { src = w6; base = 69632; cin = 64; kp_ = 576; }
    int r  = i - base;
    int co = r / kp_;
    int kp = r % kp_;
    int kk = kp / cin;
    int ci = kp % cin;
    float v = (kk < 9) ? src[(co * cin + ci) * 9 + kk] : 0.0f;
    unsigned short h, l; fsplit(v, h, l);
    Wh[i] = h; Wl[i] = l;
}

// ---------------------------------------------------------------------------
// One MFMA conv layer, LDS -> LDS. Wave mapping: nt = wid%NT (B-fragments
// loaded ONCE into registers), m-chunk = wid/NT streams m-tiles against the
// register-resident B. K fully unrolled (static B indexing, rule #20).
// In: [px][CINP=CIN+8] bf16 hi/lo. Split-bf16: 3 MFMAs (HH,HL,LH)/K-step.
// D: col=lane&15 (=co), row=4*(lane>>4)+j.
template <int WIN, int CIN, int COUT, int KP, int SO>
__device__ __forceinline__ void layerM(const unsigned short* sH, const unsigned short* sL,
                                       unsigned short* dH, unsigned short* dL,
                                       const unsigned short* __restrict__ Wh,
                                       const unsigned short* __restrict__ Wl,
                                       const float* __restrict__ bias) {
    constexpr int WOUT = WIN - 2;
    constexpr int NPX  = WOUT * WOUT;
    constexpr int CINP = CIN + 8;
    constexpr int MT   = (NPX + 15) / 16;
    constexpr int NT   = COUT / 16;          // 2 (L2,L3) or 4 (L4,L5)
    constexpr int WPN  = 4 / NT;             // waves per n-tile
    constexpr int KS   = KP / 32;

    const int wid  = threadIdx.x >> 6;
    const int lane = threadIdx.x & 63;
    const int m    = lane & 15;
    const int g    = lane >> 4;

    const int nt    = wid % NT;
    const int chunk = wid / NT;
    const int co    = nt * 16 + m;

    // B fragments for this wave's n-tile: loaded once, register-resident.
    s16x8 bH[KS], bL[KS];
    {
        const unsigned short* wbh = Wh + (size_t)co * KP + 8 * g;
        const unsigned short* wbl = Wl + (size_t)co * KP + 8 * g;
        #pragma unroll
        for (int k0 = 0; k0 < KS; ++k0) {
            bH[k0] = *(const s16x8*)(wbh + k0 * 32);
            bL[k0] = *(const s16x8*)(wbl + k0 * 32);
        }
    }
    const float bv = bias[co];

    #pragma unroll 1
    for (int mt = chunk; mt < MT; mt += WPN) {
        const int mt0 = mt * 16;
        int px = mt0 + m; if (px > NPX - 1) px = NPX - 1;
        const int pbase = (px / WOUT) * WIN + (px % WOUT);

        f32x4 aHH = {0,0,0,0}, aHL = {0,0,0,0}, aLH = {0,0,0,0};
        #pragma unroll
        for (int k0 = 0; k0 < KS; ++k0) {
            const int k   = k0 * 32 + 8 * g;
            const int kk  = k / CIN;             // power-of-2 shifts
            const int ci0 = k % CIN;
            const int aoff = (pbase + (kk / 3) * WIN + (kk % 3)) * CINP + ci0;
            s16x8 avh = *(const s16x8*)(&sH[aoff]);
            s16x8 avl = *(const s16x8*)(&sL[aoff]);
            aHH = __builtin_amdgcn_mfma_f32_16x16x32_bf16(avh, bH[k0], aHH, 0, 0, 0);
            aHL = __builtin_amdgcn_mfma_f32_16x16x32_bf16(avh, bL[k0], aHL, 0, 0, 0);
            aLH = __builtin_amdgcn_mfma_f32_16x16x32_bf16(avl, bH[k0], aLH, 0, 0, 0);
        }
        #pragma unroll
        for (int j = 0; j < 4; ++j) {
            int opx = mt0 + g * 4 + j;
            if (opx < NPX) {
                float v = fmaxf(aHH[j] + aHL[j] + aLH[j] + bv, 0.0f);
                unsigned short h, l; fsplit(v, h, l);
                dH[opx * SO + co] = h;
                dL[opx * SO + co] = l;
            }
        }
    }
}

// ---------------------------------------------------------------------------
// Fused cone + conv1(VALU) + conv2..conv5(MFMA, LDS ping-pong) + folded
// 2x2 pool -> P6 (L6's pooled A-matrix) global. Block = cell. LDS ~34KB.
__global__ __launch_bounds__(256, 2)
void fusedM(const float* __restrict__ x, const float* __restrict__ w1,
            const float* __restrict__ b1,
            const unsigned short* __restrict__ Wh, const unsigned short* __restrict__ Wl,
            const float* __restrict__ b2, const float* __restrict__ b3,
            const float* __restrict__ b4, const float* __restrict__ b5,
            unsigned short* __restrict__ P6h, unsigned short* __restrict__ P6l) {
    __shared__ float sC[592];                                    // cone [ci][196]
    __shared__ __align__(16) unsigned short AH[3840], AL[3840];  // t1[160][24] / t3[64][40] / t5[16][72]
    __shared__ __align__(16) unsigned short BH[4000], BL[4000];  // t2[100][40] / t4[36][72]

    const int cell = blockIdx.x;
    const int b = cell >> 8, gy = (cell >> 4) & 15, gx = cell & 15;

    // cone: sC[c][196]; xlow[y][x] = avg of x rows 4y+1..4y+2, cols 4x+1..4x+2.
    for (int i = threadIdx.x; i < 588; i += 256) {
        int c = i / 196, t = i % 196;
        int xi = t % 14, yi = t / 14;
        int ya = 16 * gy + 1 + yi, xa = 16 * gx + 1 + xi;
        const float* p = x + ((size_t)(b * 3 + c)) * HW1K + (4 * ya + 1) * 1024 + (4 * xa + 1);
        sC[i] = 0.25f * (p[0] + p[1] + p[1024] + p[1025]);
    }
    // zero t1 margin rows 144..159 (read by L2's kk=9 zero-weight taps)
    for (int i = threadIdx.x; i < 384; i += 256) { AH[3456 + i] = 0; AL[3456 + i] = 0; }
    __syncthreads();

    // conv1 (VALU): wave=4 co, lanes=px (3 strips). out t1 [px][24] hi/lo.
    {
        const int wid  = __builtin_amdgcn_readfirstlane(threadIdx.x >> 6);
        const int lane = threadIdx.x & 63;
        const int co0  = wid * 4;
        float acc[3][4]; int pxs[3], pb[3];
        #pragma unroll
        for (int t = 0; t < 3; ++t) {
            int px = lane + t * 64; if (px > 143) px = 143;
            pxs[t] = px; pb[t] = (px / 12) * 14 + (px % 12);
            #pragma unroll
            for (int j = 0; j < 4; ++j) acc[t][j] = b1[co0 + j];
        }
        for (int ci = 0; ci < 3; ++ci)
            #pragma unroll
            for (int k = 0; k < 9; ++k) {
                float w[4];
                #pragma unroll
                for (int j = 0; j < 4; ++j) w[j] = w1[((co0 + j) * 3 + ci) * 9 + k];
                const int ko = (k / 3) * 14 + (k % 3);
                #pragma unroll
                for (int t = 0; t < 3; ++t) {
                    float a = sC[ci * 196 + pb[t] + ko];
                    #pragma unroll
                    for (int j = 0; j < 4; ++j) acc[t][j] = fmaf(w[j], a, acc[t][j]);
                }
            }
        #pragma unroll
        for (int t = 0; t < 3; ++t)
            #pragma unroll
            for (int j = 0; j < 4; ++j) {
                float v = fmaxf(acc[t][j], 0.0f);
                unsigned short h, l; fsplit(v, h, l);
                AH[pxs[t] * 24 + co0 + j] = h;
                AL[pxs[t] * 24 + co0 + j] = l;
            }
    }
    __syncthreads();

    layerM<12, 16, 32, 160, 40>(AH, AL, BH, BL, Wh + 0,     Wl + 0,     b2);
    __syncthreads();
    layerM<10, 32, 32, 288, 40>(BH, BL, AH, AL, Wh + 5120,  Wl + 5120,  b3);
    __syncthreads();
    layerM< 8, 32, 64, 288, 72>(AH, AL, BH, BL, Wh + 14336, Wl + 14336, b4);
    __syncthreads();
    layerM< 6, 64, 64, 576, 72>(BH, BL, AH, AL, Wh + 32768, Wl + 32768, b5);
    __syncthreads();

    // folded pool: P6[cell][kk*64+ci] = 0.25 * sum_{dr,dc} t5[(kk/3+dr)*4+(kk%3+dc)][ci]
    for (int t = threadIdx.x; t < 576; t += 256) {
        int kk = t >> 6, ci = t & 63;
        int ky = kk / 3, kx = kk % 3;
        float v = 0.0f;
        #pragma unroll
        for (int dr = 0; dr < 2; ++dr)
            #pragma unroll
            for (int dc = 0; dc < 2; ++dc) {
                int px = (ky + dr) * 4 + (kx + dc);
                v += bf2f(AH[px * 72 + ci]) + bf2f(AL[px * 72 + ci]);
            }
        v *= 0.25f;
        unsigned short h, l; fsplit(v, h, l);
        P6h[(size_t)cell * 576 + t] = h;
        P6l[(size_t)cell * 576 + t] = l;
    }
}

// ---------------------------------------------------------------------------
// L6 as GEMM: M=512 cells, K=576, N=96; 1-wave blocks, grid (32, 6).
// unroll 6: 24 loads issue per batch (latency amortized at <1 wave/CU).
__global__ __launch_bounds__(64)
void gemm6(const unsigned short* __restrict__ Bh, const unsigned short* __restrict__ Bl,
           const unsigned short* __restrict__ W6h, const unsigned short* __restrict__ W6l,
           const float* __restrict__ b6, float* __restrict__ c16) {
    const int cell0 = blockIdx.x * 16;
    const int co0   = blockIdx.y * 16;
    const int lane  = threadIdx.x;
    const int m = lane & 15, g = lane >> 4;

    const unsigned short* pah = Bh  + (size_t)(cell0 + m) * 576 + 8 * g;
    const unsigned short* pal = Bl  + (size_t)(cell0 + m) * 576 + 8 * g;
    const unsigned short* pbh = W6h + (size_t)(co0 + m) * 576 + 8 * g;
    const unsigned short* pbl = W6l + (size_t)(co0 + m) * 576 + 8 * g;

    f32x4 aHH = {0,0,0,0}, aHL = {0,0,0,0}, aLH = {0,0,0,0};
    #pragma unroll 6
    for (int k0 = 0; k0 < 576; k0 += 32) {
        s16x8 avh = *(const s16x8*)(pah + k0);
        s16x8 avl = *(const s16x8*)(pal + k0);
        s16x8 bvh = *(const s16x8*)(pbh + k0);
        s16x8 bvl = *(const s16x8*)(pbl + k0);
        aHH = __builtin_amdgcn_mfma_f32_16x16x32_bf16(avh, bvh, aHH, 0, 0, 0);
        aHL = __builtin_amdgcn_mfma_f32_16x16x32_bf16(avh, bvl, aHL, 0, 0, 0);
        aLH = __builtin_amdgcn_mfma_f32_16x16x32_bf16(avl, bvh, aLH, 0, 0, 0);
    }
    const int co = co0 + m;
    const float bv = b6[co];
    #pragma unroll
    for (int j = 0; j < 4; ++j) {
        int cell = cell0 + g * 4 + j;
        float v = aHH[j] + aHL[j] + aLH[j] + bv;
        int b = cell >> 8, gyx = cell & 255;
        c16[(size_t)b * 24576 + (gyx * 8 + (co & 7)) * 12 + (co >> 3)] = v;
    }
}

// ---------------------------------------------------------------------------
// Fused guide + trilinear slice + affine + clip; 4 px per thread.
__global__ __launch_bounds__(256)
void slice_apply4(const float* __restrict__ x, const float* __restrict__ c16,
                  float* __restrict__ out) {
    int t = blockIdx.x * 256 + threadIdx.x;
    int po4 = t * 4;
    int b   = po4 >> 20;
    int po  = po4 & (HW1K - 1);
    int py  = po >> 10;
    int px0 = po & 1023;

    const float* xb = x + (size_t)b * 3 * HW1K;
    f4 rv  = *(const f4*)(xb + po);
    f4 gv  = *(const f4*)(xb + HW1K + po);
    f4 bv  = *(const f4*)(xb + 2 * HW1K + po);

    float ysf = (float)py * (15.0f / 1023.0f);
    int y0 = (int)floorf(ysf); int y1 = min(y0 + 1, 15);
    float wy = ysf - (float)y0;

    const float* gb = c16 + (size_t)b * 24576;
    f4 outv[3];

    #pragma unroll
    for (int s = 0; s < 4; ++s) {
        float r  = rv[s], g = gv[s], bl = bv[s];
        int   px = px0 + s;

        float gd = fminf(fmaxf(0.299f * r + 0.587f * g + 0.114f * bl, 0.0f), 1.0f);

        float xsf = (float)px * (15.0f / 1023.0f);
        int x0 = (int)floorf(xsf); int x1 = min(x0 + 1, 15);
        float wx = xsf - (float)x0;

        float d  = gd * 7.0f;
        int d0 = (int)floorf(d); d0 = max(0, min(d0, 7));
        int d1 = min(d0 + 1, 7);
        float wd = fminf(fmaxf(d - (float)d0, 0.0f), 1.0f);

        float co[12];
        #pragma unroll
        for (int p = 0; p < 12; ++p) co[p] = 0.0f;

        #pragma unroll
        for (int cy = 0; cy < 2; ++cy) {
            int   yy  = cy ? y1 : y0;
            float wyf = cy ? wy : 1.0f - wy;
            #pragma unroll
            for (int cx = 0; cx < 2; ++cx) {
                int   xx  = cx ? x1 : x0;
                float wyx = wyf * (cx ? wx : 1.0f - wx);
                const float* g0 = gb + ((yy * 16 + xx) * 8 + d0) * 12;
                const float* g1 = gb + ((yy * 16 + xx) * 8 + d1) * 12;
                float wA = wyx * (1.0f - wd), wB = wyx * wd;
                #pragma unroll
                for (int p = 0; p < 12; ++p) co[p] += wA * g0[p] + wB * g1[p];
            }
        }

        #pragma unroll
        for (int i = 0; i < 3; ++i) {
            float v = co[i * 4 + 0] * r + co[i * 4 + 1] * g + co[i * 4 + 2] * bl + co[i * 4 + 3];
            outv[i][s] = fminf(fmaxf(v, 0.0f), 1.0f);
        }
    }

    float* ob = out + (size_t)b * 3 * HW1K;
    #pragma unroll
    for (int i = 0; i < 3; ++i)
        *(f4*)(ob + i * HW1K + po) = outv[i];
}

// ---------------------------------------------------------------------------
extern "C" void kernel_launch(void* const* d_in, const int* in_sizes, int n_in,
                              void* d_out, int out_size, void* d_ws, size_t ws_size,
                              hipStream_t stream) {
    const float* x  = (const float*)d_in[0];
    const float* w1 = (const float*)d_in[1];  const float* b1 = (const float*)d_in[2];
    const float* w2 = (const float*)d_in[3];  const float* b2 = (const float*)d_in[4];
    const float* w3 = (const float*)d_in[5];  const float* b3 = (const float*)d_in[6];
    const float* w4 = (const float*)d_in[7];  const float* b4 = (const float*)d_in[8];
    const float* w5 = (const float*)d_in[9];  const float* b5 = (const float*)d_in[10];
    const float* w6 = (const float*)d_in[11]; const float* b6 = (const float*)d_in[12];
    float* out = (float*)d_out;

    char* w = (char*)d_ws;
    unsigned short* Wh  = (unsigned short*)w;   w += 124928 * 2;
    unsigned short* Wl  = (unsigned short*)w;   w += 124928 * 2;
    unsigned short* P6h = (unsigned short*)w;   w += 512 * 576 * 2;
    unsigned short* P6l = (unsigned short*)w;   w += 512 * 576 * 2;
    float*          c16 = (float*)w;

    prep_wM<<<dim3(489),  dim3(256), 0, stream>>>(w2, w3, w4, w5, w6, Wh, Wl);
    fusedM <<<dim3(512),  dim3(256), 0, stream>>>(x, w1, b1, Wh, Wl, b2, b3, b4, b5, P6h, P6l);
    gemm6  <<<dim3(32, 6), dim3(64), 0, stream>>>(P6h, P6l, Wh + 69632, Wl + 69632, b6, c16);
    slice_apply4<<<dim3(2 * HW1K / 4 / 256), dim3(256), 0, stream>>>(x, c16, out);

    (void)in_sizes; (void)n_in; (void)out_size; (void)ws_size;
}